// Round 3
// baseline (463.498 us; speedup 1.0000x reference)
//
#include <hip/hip_runtime.h>

// Spherical harmonics, L=20 (400 cols), B=250000, fp32 out.
// R5: store-pipelined chunk design.
//  - 7 column chunks by l-range (even-l boundaries -> C0 % 4 == 0, aligned
//    float4 stores): l=[0,6),[6,10),[10,12),[12,14),[14,16),[16,18),[18,20)
//    cols C0={0,36,100,144,196,256,324}, W={36,64,44,52,60,68,76}.
//  - double-buffered LDS (2 x 64 x 77 floats = 39.4KB) -> 4 blocks/CU
//    (was 3), __launch_bounds__(256,4).
//  - raw barriers: s_waitcnt lgkmcnt(0) + s_barrier, NO vmcnt(0) drain ->
//    global stores stay in flight across barriers (m201/T4 pattern);
//    output is never read so only LDS needs barrier ordering.
//  - per interval: flush chunk k-1 (stores issued first) || compute chunk k
//    into the other buffer -> store latency hides under VALU.
//  - Legendre chain state (p1,p2 per owned m) carried in registers across
//    chunks; static slot index (m>>2) keeps arrays in VGPRs.
// Stride 77 (77 mod 32 = 13, coprime): emit writes 2-way (free), flush
// reads <=3-way.

#define L_MAX 20
#define NCOL 400
#define PTS 64          // points per block (= lane)
#define TPB 256         // 4 waves
#define LSTR 77         // LDS buffer col stride (floats)

// ---- compile-time double sqrt via Newton ----
constexpr double csqrt(double x) {
    double g = (x > 1.0) ? x : 1.0;
    for (int i = 0; i < 200; ++i) g = 0.5 * (g + x / g);
    return g;
}

struct CoefTbl { float c[NCOL]; };

constexpr CoefTbl make_tbl() {
    CoefTbl t{};
    const double PI  = 3.14159265358979323846;
    const double SQ2 = csqrt(2.0);
    for (int l = 0; l < L_MAX; ++l) {
        for (int m = 0; m <= l; ++m) {
            double r = 1.0;
            for (int k = l - m + 1; k <= l + m; ++k) r /= (double)k;
            double K = csqrt((2.0 * l + 1.0) / (4.0 * PI) * r);
            int base = l * l + l;
            if (m == 0) {
                t.c[base] = (float)K;
            } else {
                t.c[base + m] = (float)(SQ2 * K);
                t.c[base - m] = (float)(SQ2 * K);
            }
        }
    }
    return t;
}

static constexpr CoefTbl TBL = make_tbl();

// m -> wave assignment (5 m's per wave, globally balanced); slot = m>>2.
__device__ constexpr int SUBOF[L_MAX] =
    {0,1,2,3, 3,2,1,0, 0,1,2,3, 3,2, 1,0,0,1, 2,3};

// Barrier WITHOUT vmcnt drain: LDS ordering only; stores stay in flight.
#define BARRIER() do {                                      \
    asm volatile("s_waitcnt lgkmcnt(0)" ::: "memory");      \
    __builtin_amdgcn_s_barrier();                           \
    asm volatile("" ::: "memory");                          \
} while (0)

// Compute cols of l in [L0,L1) into myrow (local col = l*l+l +- m - C0).
// Chain state p1 = P[l,m], p2 = P[l-1,m] per owned-m slot, carried across
// calls. All indices compile-time after unrolling (SUBOF[m] folds).
template<int L0, int L1, int C0>
__device__ __forceinline__ void computeChunk(int sub, float x,
        float (&p1)[5], float (&p2)[5], const float (&pmmv)[5],
        const float (&cmv)[5], const float (&smv)[5],
        float* __restrict__ myrow) {
#pragma unroll
    for (int l = L0; l < L1; ++l) {
        const int g = l * l + l;
#pragma unroll
        for (int m = 0; m <= l; ++m) {
            if (SUBOF[m] != sub) continue;   // wave-uniform branch
            const int s = m >> 2;            // compile-time slot
            float pv;
            if (l == m) {
                pv = pmmv[s];                // P[m,m]
                p1[s] = pv;
            } else if (l == m + 1) {
                pv = float(2 * m + 1) * x * p1[s];   // P[m+1,m]
                p2[s] = p1[s];
                p1[s] = pv;
            } else {
                pv = (float(2 * l - 1) * x * p1[s] -
                      float(l + m - 1) * p2[s]) * (1.0f / float(l - m));
                p2[s] = p1[s];
                p1[s] = pv;
            }
            const int b = g - C0;
            if (m == 0) {
                myrow[b] = TBL.c[g] * pv;
            } else {
                const float t = TBL.c[g + m] * pv;
                myrow[b + m] = t * cmv[s];
                myrow[b - m] = t * smv[s];
            }
        }
    }
}

// Flush W cols (mult of 4) at global col C0 (mult of 4) from src buffer.
// 16B/lane: 4 LDS floats -> one aligned global_store_dwordx4.
template<int C0, int W>
__device__ __forceinline__ void flushChunk(const float* __restrict__ src,
                                           float* __restrict__ outBase,
                                           int tid, int rem) {
    constexpr int G = W / 4;          // float4 groups per row
    constexpr int N = PTS * G;        // N % 64 == 0 -> wave-uniform tail
    if (rem >= PTS) {
        for (int i = tid; i < N; i += TPB) {
            int pp = i / G;                   // constant divisor -> magic mul
            int cc = (i - pp * G) * 4;
            const float* s = src + pp * LSTR + cc;
            float4 v = make_float4(s[0], s[1], s[2], s[3]);
            *reinterpret_cast<float4*>(outBase + pp * NCOL + C0 + cc) = v;
        }
    } else {
        for (int i = tid; i < N; i += TPB) {
            int pp = i / G;
            int cc = (i - pp * G) * 4;
            if (pp < rem) {
                const float* s = src + pp * LSTR + cc;
                float4 v = make_float4(s[0], s[1], s[2], s[3]);
                *reinterpret_cast<float4*>(outBase + pp * NCOL + C0 + cc) = v;
            }
        }
    }
}

__global__ __launch_bounds__(TPB, 4) void sh_kernel(const float2* __restrict__ lonlat,
                                                    float* __restrict__ out, int B) {
    __shared__ float tile[2][PTS * LSTR];   // 39,424 B -> 4 blocks/CU

    const int tid  = threadIdx.x;
    const int lane = tid & 63;     // point within block
    const int sub  = tid >> 6;     // wave id (uniform per wave)
    const int blockBase = blockIdx.x * PTS;
    const int rem = B - blockBase;
    const int p  = blockBase + lane;
    const int pr = p < B ? p : B - 1;

    float2 ll = lonlat[pr];
    const float D2R = 0.017453292519943295f;
    float phi   = (ll.x + 180.0f) * D2R;
    float theta = (ll.y + 90.0f) * D2R;

    float x, sx, s1, c1;
    sincosf(theta, &sx, &x);   // sx = sin(theta), x = cos(theta)
    sincosf(phi, &s1, &c1);

    // Per-owned-m state: P[m,m] start, cos/sin(m*phi). Slot = m>>2.
    float p1[5], p2[5], pmmv[5], cmv[5], smv[5];
#pragma unroll
    for (int s = 0; s < 5; ++s) { p1[s]=0.f; p2[s]=0.f; pmmv[s]=0.f; cmv[s]=0.f; smv[s]=0.f; }
    {
        float pm = 1.0f, cv = 1.0f, sv = 0.0f;
#pragma unroll
        for (int m = 0; m < L_MAX; ++m) {
            if (SUBOF[m] == sub) {
                const int s = m >> 2;
                pmmv[s] = pm; cmv[s] = cv; smv[s] = sv;
            }
            if (m < L_MAX - 1) {
                pm = -float(2 * m + 1) * sx * pm;
                float cn = cv * c1 - sv * s1;
                sv = sv * c1 + cv * s1;
                cv = cn;
            }
        }
    }

    float* row0 = &tile[0][lane * LSTR];
    float* row1 = &tile[1][lane * LSTR];
    float* outBase = out + (size_t)blockBase * NCOL;

    // ---- pipelined chunk sequence: flush k-1 (stores first) || compute k ----
    computeChunk<0, 6, 0>(sub, x, p1, p2, pmmv, cmv, smv, row0);
    BARRIER();

    flushChunk<0, 36>(tile[0], outBase, tid, rem);
    computeChunk<6, 10, 36>(sub, x, p1, p2, pmmv, cmv, smv, row1);
    BARRIER();

    flushChunk<36, 64>(tile[1], outBase, tid, rem);
    computeChunk<10, 12, 100>(sub, x, p1, p2, pmmv, cmv, smv, row0);
    BARRIER();

    flushChunk<100, 44>(tile[0], outBase, tid, rem);
    computeChunk<12, 14, 144>(sub, x, p1, p2, pmmv, cmv, smv, row1);
    BARRIER();

    flushChunk<144, 52>(tile[1], outBase, tid, rem);
    computeChunk<14, 16, 196>(sub, x, p1, p2, pmmv, cmv, smv, row0);
    BARRIER();

    flushChunk<196, 60>(tile[0], outBase, tid, rem);
    computeChunk<16, 18, 256>(sub, x, p1, p2, pmmv, cmv, smv, row1);
    BARRIER();

    flushChunk<256, 68>(tile[1], outBase, tid, rem);
    computeChunk<18, 20, 324>(sub, x, p1, p2, pmmv, cmv, smv, row0);
    BARRIER();

    flushChunk<324, 76>(tile[0], outBase, tid, rem);
}

extern "C" void kernel_launch(void* const* d_in, const int* in_sizes, int n_in,
                              void* d_out, int out_size, void* d_ws, size_t ws_size,
                              hipStream_t stream) {
    (void)n_in; (void)d_ws; (void)ws_size; (void)out_size;
    const float2* lonlat = (const float2*)d_in[0];
    float* out = (float*)d_out;
    int B = in_sizes[0] / 2;

    const int blocks = (B + PTS - 1) / PTS;
    sh_kernel<<<blocks, TPB, 0, stream>>>(lonlat, out, B);
}

// Round 4
// 443.190 us; speedup vs baseline: 1.0458x; 1.0458x over previous
//
#include <hip/hip_runtime.h>

// Spherical harmonics, L=20 (400 cols), B=250000, fp32 out.
// R6 = R4 (best, 446us) + two surgical fixes, all else identical:
//  1. lgkm-only barriers (s_waitcnt lgkmcnt(0); s_barrier) instead of
//     __syncthreads(): no vmcnt(0) drain, so flush stores stay in flight
//     across barriers and drain under the next compute phase (T4 pattern,
//     correctness proven in R5).
//  2. Software-pipelined flush: uniform 12-iter main body, all 12 float4
//     LDS reads issued before the 12 dwordx4 stores (static-indexed regs),
//     wave-uniform tail branch. Breaks the per-iteration ds_read->store
//     latency chain R4 only partially hid with unroll-4.
// Structure: 64 pts/block, 256 thr (4 waves), one 64x205 LDS tile reused
// by two column chunks [0,196) and [196,400); m-partitioned compute
// (SUBOF) so each wave computes only its own Legendre chains.

#define L_MAX 20
#define NCOL 400
#define PTS 64          // points per block
#define TPB 256         // 4 waves
#define LSTR 205        // LDS row stride; 205 mod 32 = 13, coprime -> conflict-free
#define SPLIT_L 14      // 14*14 = 196
#define C0A 0
#define CA 196
#define C0B 196
#define CB 204

// ---- compile-time double sqrt via Newton ----
constexpr double csqrt(double x) {
    double g = (x > 1.0) ? x : 1.0;
    for (int i = 0; i < 200; ++i) g = 0.5 * (g + x / g);
    return g;
}

struct CoefTbl { float c[NCOL]; };

constexpr CoefTbl make_tbl() {
    CoefTbl t{};
    const double PI  = 3.14159265358979323846;
    const double SQ2 = csqrt(2.0);
    for (int l = 0; l < L_MAX; ++l) {
        for (int m = 0; m <= l; ++m) {
            double r = 1.0;
            for (int k = l - m + 1; k <= l + m; ++k) r /= (double)k;
            double K = csqrt((2.0 * l + 1.0) / (4.0 * PI) * r);
            int base = l * l + l;
            if (m == 0) {
                t.c[base] = (float)K;
            } else {
                t.c[base + m] = (float)(SQ2 * K);
                t.c[base - m] = (float)(SQ2 * K);
            }
        }
    }
    return t;
}

static constexpr CoefTbl TBL = make_tbl();

// m -> wave assignment, balanced across both passes.
__device__ constexpr int SUBOF[L_MAX] =
    {0,1,2,3, 3,2,1,0, 0,1,2,3, 3,2, 1,0,0,1, 2,3};

// Barrier WITHOUT vmcnt drain: LDS ordering only; stores stay in flight.
#define BARRIER() do {                                      \
    asm volatile("s_waitcnt lgkmcnt(0)" ::: "memory");      \
    __builtin_amdgcn_s_barrier();                           \
    asm volatile("" ::: "memory");                          \
} while (0)

// One column-chunk pass: run every owned m-chain, emit cols with
// L0 <= l < L1 into the LDS row at (global col - C0).
template<int L0, int L1, int C0>
__device__ __forceinline__ void sh_pass(int sub, float x, float sx,
                                        float c1, float s1,
                                        float* __restrict__ myrow) {
    constexpr int LTOP = L1 - 1;     // last l this pass ever emits
    float pm = 1.0f;                 // P[m,m] sweep
    float cv = 1.0f, sv = 0.0f;      // cos(m*phi), sin(m*phi) sweep

    auto emit = [&](int l, int m, float p) {
        if (l < L0) return;          // folds at compile time (unrolled)
        const int g = l * l + l;
        const int b = g - C0;
        if (m == 0) {
            myrow[b] = TBL.c[g] * p;
        } else {
            const float t = TBL.c[g + m] * p;
            myrow[b + m] = t * cv;
            myrow[b - m] = t * sv;
        }
    };

#pragma unroll
    for (int m = 0; m <= LTOP; ++m) {
        if (SUBOF[m] == sub) {       // wave-uniform branch
            float p2 = pm;           // P[m,m]
            emit(m, m, p2);
            if (m + 1 <= LTOP) {
                float p1 = float(2 * m + 1) * x * p2;   // P[m+1,m]
                emit(m + 1, m, p1);
#pragma unroll
                for (int l = m + 2; l <= LTOP; ++l) {
                    float p0 = (float(2 * l - 1) * x * p1 -
                                float(l + m - 1) * p2) *
                               (1.0f / float(l - m));
                    emit(l, m, p0);
                    p2 = p1; p1 = p0;
                }
            }
        }
        if (m < LTOP) {              // advance sweeps (all waves)
            pm = -float(2 * m + 1) * sx * pm;
            float cn = cv * c1 - sv * s1;
            sv = sv * c1 + cv * s1;
            cv = cn;
        }
    }
}

// Flush W cols (mult of 4) at global col C0 (mult of 4).
// Software-pipelined: all MAIN float4 LDS reads issued, then all stores.
template<int C0, int W>
__device__ __forceinline__ void flushChunk(const float* __restrict__ src,
                                           float* __restrict__ outBase,
                                           int tid, int rem) {
    constexpr int G    = W / 4;        // float4 groups per row
    constexpr int N    = PTS * G;
    constexpr int MAIN = N / TPB;      // uniform iterations (12)
    constexpr int TAIL = N - MAIN * TPB;

    if (rem >= PTS) {
        float4 v[MAIN];
        int off[MAIN];
#pragma unroll
        for (int k = 0; k < MAIN; ++k) {
            int i  = tid + k * TPB;
            int pp = i / G;                  // constant divisor -> magic mul
            int cc = (i - pp * G) * 4;
            const float* s = src + pp * LSTR + cc;
            v[k]   = make_float4(s[0], s[1], s[2], s[3]);
            off[k] = pp * NCOL + C0 + cc;
        }
#pragma unroll
        for (int k = 0; k < MAIN; ++k)
            *reinterpret_cast<float4*>(outBase + off[k]) = v[k];
        if (TAIL > 0 && tid < TAIL) {
            int i  = MAIN * TPB + tid;
            int pp = i / G;
            int cc = (i - pp * G) * 4;
            const float* s = src + pp * LSTR + cc;
            float4 t = make_float4(s[0], s[1], s[2], s[3]);
            *reinterpret_cast<float4*>(outBase + pp * NCOL + C0 + cc) = t;
        }
    } else {
        for (int i = tid; i < N; i += TPB) {
            int pp = i / G;
            int cc = (i - pp * G) * 4;
            if (pp < rem) {
                const float* s = src + pp * LSTR + cc;
                float4 t = make_float4(s[0], s[1], s[2], s[3]);
                *reinterpret_cast<float4*>(outBase + pp * NCOL + C0 + cc) = t;
            }
        }
    }
}

__global__ __launch_bounds__(TPB, 3) void sh_kernel(const float2* __restrict__ lonlat,
                                                    float* __restrict__ out, int B) {
    __shared__ float tile[PTS * LSTR];

    const int tid  = threadIdx.x;
    const int lane = tid & 63;     // point within block
    const int sub  = tid >> 6;     // wave id (uniform per wave)
    const int blockBase = blockIdx.x * PTS;
    const int rem = B - blockBase;
    const int p  = blockBase + lane;
    const int pr = p < B ? p : B - 1;

    float2 ll = lonlat[pr];
    const float D2R = 0.017453292519943295f;
    float phi   = (ll.x + 180.0f) * D2R;
    float theta = (ll.y + 90.0f) * D2R;

    float x, sx, s1, c1;
    sincosf(theta, &sx, &x);   // sx = sin(theta), x = cos(theta)
    sincosf(phi, &s1, &c1);

    float* myrow = tile + lane * LSTR;
    float* outBase = out + (size_t)blockBase * NCOL;

    // ---- chunk A: l = 0..13 -> global cols [0,196) ----
    sh_pass<0, SPLIT_L, C0A>(sub, x, sx, c1, s1, myrow);

    BARRIER();
    flushChunk<C0A, CA>(tile, outBase, tid, rem);
    BARRIER();

    // ---- chunk B: l = 14..19 -> global cols [196,400), stored at col-196 ----
    sh_pass<SPLIT_L, L_MAX, C0B>(sub, x, sx, c1, s1, myrow);

    BARRIER();
    flushChunk<C0B, CB>(tile, outBase, tid, rem);
}

extern "C" void kernel_launch(void* const* d_in, const int* in_sizes, int n_in,
                              void* d_out, int out_size, void* d_ws, size_t ws_size,
                              hipStream_t stream) {
    (void)n_in; (void)d_ws; (void)ws_size; (void)out_size;
    const float2* lonlat = (const float2*)d_in[0];
    float* out = (float*)d_out;
    int B = in_sizes[0] / 2;

    const int blocks = (B + PTS - 1) / PTS;
    sh_kernel<<<blocks, TPB, 0, stream>>>(lonlat, out, B);
}